// Round 2
// baseline (195.494 us; speedup 1.0000x reference)
//
#include <hip/hip_runtime.h>
#include <cmath>
#include <cfloat>

// Problem constants (fixed by setup_inputs: B=4, Q=100, K=17, H=W=128).
constexpr int NB = 4;
constexpr int NQ = 100;
constexpr int NK = 17;
constexpr int NH = 128;
constexpr int NW = 128;

constexpr float HUMAN_CONF = 0.7f;
constexpr float KP_CONF    = 0.5f;
constexpr float NMS_THR    = 0.5f;

// Output layout (flat float32, reference return order):
//   scores  [NB*NQ]          offset 0
//   boxes   [NB*NQ*4]        offset NB*NQ
//   kps     [NB*NQ*NK*3]     offset NB*NQ*5
//   keep    [NB*NQ]          offset NB*NQ*5 + NB*NQ*NK*3
constexpr int OFF_BOXES = NB * NQ;
constexpr int OFF_KPS   = NB * NQ * 5;
constexpr int OFF_KEEP  = NB * NQ * 5 + NB * NQ * NK * 3;

// Handoff flags: two distinct NON-repeated-byte magics per batch. A harness
// poison fill writes a repeated byte pattern -> can never equal either magic.
constexpr unsigned MAGIC1 = 0x1F2E3D4Cu;
constexpr unsigned MAGIC2 = 0xC0FFEE42u;

constexpr int NBLK = 1024;   // 4 blocks/CU on 256 CUs -> ALL co-resident (no deadlock)

// ---------------- Fused kernel ----------------
// Blocks 0..3: score/softmax + NMS + outputs + compact live list for batch b,
// then release-publish flags. All blocks: spin-acquire on the 4 flag pairs
// (spinners meanwhile warm LLC with the heatmaps the poison just evicted),
// then grid-stride one wave per live (box, keypoint) item.
__global__ __launch_bounds__(128) void fused_kernel(
    const float* __restrict__ logits,   // [NB,NQ,2]
    const float* __restrict__ pboxes,   // [NB,NQ,4] cxcywh in [0,1]
    const float* __restrict__ hm,       // [NB,NK,NH,NW]
    const int* __restrict__ img_h_p,    // scalar
    const int* __restrict__ img_w_p,    // scalar
    float* __restrict__ out,            // 22800 floats
    unsigned* __restrict__ flags,       // ws: [8]
    int* __restrict__ wcount,           // ws: [NB] live count per batch
    int2* __restrict__ wlist)           // ws: [NB*NQ] (packed x1|y1<<8|x2<<16|y2<<24, gi)
{
    const int blk = blockIdx.x;
    const int t   = threadIdx.x;

    __shared__ float sbx[NQ][4];          // xyxy image coords, original order
    __shared__ float ssc[NQ];             // softmax max prob
    __shared__ unsigned char sval[NQ];    // valid flag
    __shared__ int   sorder[NQ];          // sorted pos -> original idx
    __shared__ float sortb[NQ][4];        // boxes in sorted order
    __shared__ float sarea[NQ];
    __shared__ unsigned char ssv[NQ];     // valid in sorted order
    __shared__ unsigned long long smask0[NQ], smask1[NQ]; // IoU>thr bitmask per sorted row
    __shared__ unsigned long long skmask[2];              // keep bits (sorted positions)
    __shared__ unsigned long long svb[2];                 // sorted-valid ballot per wave
    __shared__ unsigned long long swl0;                   // wave-0 live ballot

    if (blk >= NB) {
        // ---- LLC/L2 warm: one 64B cache line per lane covers all 4.45 MB of
        // heatmap while the NMS blocks run. Poison just evicted everything.
        const int line = (blk - NB) * 128 + t;            // 64B line id
        if (line < (NB * NK * NH * NW) / 16) {
            const float4 v = ((const float4*)hm)[line * 4];
            asm volatile("" :: "v"(v.x), "v"(v.w));       // keep load live
        }
    } else {
        // ================= NMS phase (verified path, batch b = blk) =================
        const int b = blk;

        // Zero-fill this batch's kps slice (NQ*NK*3 = 5100 floats = 1275 float4).
        {
            float4* kz4 = (float4*)(out + OFF_KPS + b * (NQ * NK * 3));
            const float4 z4 = make_float4(0.0f, 0.0f, 0.0f, 0.0f);
            for (int i = t; i < (NQ * NK * 3) / 4; i += 128) kz4[i] = z4;
        }

        const float iw = (float)img_w_p[0];
        const float ih = (float)img_h_p[0];
        const float sxl = (float)NW / iw;     // 0.25 exact for 512
        const float syl = (float)NH / ih;

        if (t < NQ) {
            // softmax over 2 classes; score = max prob, label==0 iff l0 >= l1
            const float l0 = logits[(b * NQ + t) * 2 + 0];
            const float l1 = logits[(b * NQ + t) * 2 + 1];
            const float m  = fmaxf(l0, l1);
            const float e0 = expf(l0 - m);
            const float e1 = expf(l1 - m);
            const float score = fmaxf(e0, e1) / (e0 + e1);
            const bool  lab0  = (l0 >= l1);

            const float cx = pboxes[(b * NQ + t) * 4 + 0];
            const float cy = pboxes[(b * NQ + t) * 4 + 1];
            const float w  = pboxes[(b * NQ + t) * 4 + 2];
            const float h  = pboxes[(b * NQ + t) * 4 + 3];
            sbx[t][0] = (cx - 0.5f * w) * iw;
            sbx[t][1] = (cy - 0.5f * h) * ih;
            sbx[t][2] = (cx + 0.5f * w) * iw;
            sbx[t][3] = (cy + 0.5f * h) * ih;
            ssc[t]  = score;
            sval[t] = (lab0 && score >= HUMAN_CONF) ? 1 : 0;
        }
        __syncthreads();

        // Rank by (key desc, index desc) == reverse of stable ascending argsort.
        if (t < NQ) {
            const float key = sval[t] ? ssc[t] : -INFINITY;
            int rank = 0;
            for (int j = 0; j < NQ; ++j) {
                const float kj = sval[j] ? ssc[j] : -INFINITY;
                if (kj > key || (kj == key && j > t)) rank++;
            }
            sorder[rank] = t;
        }
        __syncthreads();

        if (t < NQ) {
            const int oi = sorder[t];
            const float x1 = sbx[oi][0], y1 = sbx[oi][1], x2 = sbx[oi][2], y2 = sbx[oi][3];
            sortb[t][0] = x1; sortb[t][1] = y1; sortb[t][2] = x2; sortb[t][3] = y2;
            sarea[t] = fmaxf(x2 - x1, 0.0f) * fmaxf(y2 - y1, 0.0f);
            ssv[t]   = sval[oi];
        }
        __syncthreads();

        // Each sorted row t: bitmask over columns j with IoU(t,j) > thr.
        if (t < NQ) {
            unsigned long long m0 = 0ull, m1 = 0ull;
            const float ax1 = sortb[t][0], ay1 = sortb[t][1], ax2 = sortb[t][2], ay2 = sortb[t][3];
            const float aa = sarea[t];
            for (int j = 0; j < NQ; ++j) {
                const float lx = fmaxf(ax1, sortb[j][0]);
                const float ly = fmaxf(ay1, sortb[j][1]);
                const float rx = fminf(ax2, sortb[j][2]);
                const float ry = fminf(ay2, sortb[j][3]);
                const float wv = fmaxf(rx - lx, 0.0f);
                const float hv = fmaxf(ry - ly, 0.0f);
                const float inter = wv * hv;
                const float uni = aa + sarea[j] - inter;
                const float iou = inter / fmaxf(uni, 1e-9f);
                if (iou > NMS_THR) {
                    if (j < 64) m0 |= 1ull << j; else m1 |= 1ull << (j - 64);
                }
            }
            smask0[t] = m0; smask1[t] = m1;
        }

        // Sorted-valid ballot (valid boxes occupy a prefix of sorted order).
        {
            const bool sv = (t < NQ) ? (ssv[t] != 0) : false;
            const unsigned long long vb = __ballot(sv);
            if ((t & 63) == 0) svb[t >> 6] = vb;
        }
        __syncthreads();

        // ffs-driven greedy over bitmasks (thread 0): one iteration per KEPT box.
        if (t == 0) {
            unsigned long long rem0 = svb[0], rem1 = svb[1];
            unsigned long long k0 = 0ull, k1 = 0ull;
            while (rem0 | rem1) {
                int i;
                unsigned long long bit0 = 0ull, bit1 = 0ull;
                if (rem0) { i = __builtin_ctzll(rem0); bit0 = 1ull << i; }
                else      { const int j = __builtin_ctzll(rem1); i = 64 + j; bit1 = 1ull << j; }
                k0 |= bit0; k1 |= bit1;
                rem0 &= ~(smask0[i] | bit0);
                rem1 &= ~(smask1[i] | bit1);
            }
            skmask[0] = k0; skmask[1] = k1;
        }
        __syncthreads();

        // Write scores/boxes/keep outputs + compact live list.
        int  kp = 0, gi = 0;
        int  x1i = 0, y1i = 0, x2i = 0, y2i = 0;
        bool live = false;

        if (t < NQ) {
            const int oi = sorder[t];
            kp = (t < 64) ? (int)((skmask[0] >> t) & 1ull)
                          : (int)((skmask[1] >> (t - 64)) & 1ull);
            gi = b * NQ + oi;

            out[gi] = ssc[oi] * (float)kp;

            const int bi0 = (int)sbx[oi][0];   // trunc toward zero == astype(int32)
            const int bi1 = (int)sbx[oi][1];
            const int bi2 = (int)sbx[oi][2];
            const int bi3 = (int)sbx[oi][3];
            out[OFF_BOXES + gi * 4 + 0] = (float)(bi0 * kp);
            out[OFF_BOXES + gi * 4 + 1] = (float)(bi1 * kp);
            out[OFF_BOXES + gi * 4 + 2] = (float)(bi2 * kp);
            out[OFF_BOXES + gi * 4 + 3] = (float)(bi3 * kp);

            out[OFF_KEEP + gi] = (float)kp;

            // ROI bounds: int * 0.25f exact; trunc toward zero matches astype(int32).
            x1i = max((int)((float)bi0 * sxl), 0);
            y1i = max((int)((float)bi1 * syl), 0);
            x2i = min((int)((float)bi2 * sxl) + 1, NW);
            y2i = min((int)((float)bi3 * syl) + 1, NH);
            live = kp && (x2i > x1i) && (y2i > y1i);   // empty-ROI kept boxes stay zero
        }

        // Compact live entries: rank = #live threads with smaller t (2-wave prefix).
        const unsigned long long lm = __ballot(live);
        if (t == 0) swl0 = lm;
        __syncthreads();
        if (t == 64) wcount[b] = __popcll(swl0) + __popcll(lm);
        const int lane = t & 63;
        const unsigned long long below = lm & ((lane ? (1ull << lane) : 1ull) - 1ull);
        const int rank = (t < 64) ? __popcll(below) : __popcll(swl0) + __popcll(below);
        if (live) {
            const int pack = x1i | (y1i << 8) | (x2i << 16) | (y2i << 24);  // all in [0,128]
            wlist[b * NQ + rank] = make_int2(pack, gi);
        }

        // Publish: all block writes happened-before this barrier; the agent-scope
        // release stores then make them device-visible along with the flags.
        __syncthreads();
        if (t == 0) {
            __hip_atomic_store(&flags[2 * b + 0], MAGIC1, __ATOMIC_RELEASE, __HIP_MEMORY_SCOPE_AGENT);
            __hip_atomic_store(&flags[2 * b + 1], MAGIC2, __ATOMIC_RELEASE, __HIP_MEMORY_SCOPE_AGENT);
        }
    }

    // ---- Spin until all 4 batches published (thread 0 polls; barrier broadcasts).
    // All NBLK blocks are co-resident by construction -> cannot deadlock.
    if (t == 0) {
        for (;;) {
            bool ok = true;
            #pragma unroll
            for (int i = 0; i < NB; ++i) {
                ok &= (__hip_atomic_load(&flags[2 * i + 0], __ATOMIC_ACQUIRE, __HIP_MEMORY_SCOPE_AGENT) == MAGIC1);
                ok &= (__hip_atomic_load(&flags[2 * i + 1], __ATOMIC_ACQUIRE, __HIP_MEMORY_SCOPE_AGENT) == MAGIC2);
            }
            if (ok) break;
            __builtin_amdgcn_s_sleep(8);
        }
    }
    __syncthreads();

    // ================= KPS phase: one wave per live (box, keypoint) item =================
    const int c0 = wcount[0] * NK;
    const int c1 = wcount[1] * NK;
    const int c2 = wcount[2] * NK;
    const int c3 = wcount[3] * NK;
    const int t0 = c0, t1 = c0 + c1, t2 = t1 + c2, T = t2 + c3;

    const int lane = t & 63;
    const int wv   = blk * 2 + (t >> 6);          // global wave id, stride NBLK*2
    const float sx = (float)NW / (float)img_w_p[0];
    const float sy = (float)NH / (float)img_h_p[0];

    for (int item = wv; item < T; item += NBLK * 2) {
        int b, base;
        if (item < t1) { if (item < t0) { b = 0; base = 0;  } else { b = 1; base = t0; } }
        else           { if (item < t2) { b = 2; base = t1; } else { b = 3; base = t2; } }
        const int local = item - base;
        const int r = local / NK;            // const divisor -> magic mul
        const int k = local - r * NK;

        const int2 wl = wlist[b * NQ + r];
        const int x1 = wl.x & 255;
        const int y1 = (wl.x >> 8) & 255;
        const int x2 = (wl.x >> 16) & 255;
        const int y2 = (wl.x >> 24) & 255;
        const int gi = wl.y;

        const float4* __restrict__ b4 =
            (const float4*)(hm + (size_t)(b * NK + k) * (NH * NW));   // 64KB-aligned

        const int xa     = x1 & ~3;                     // align ROI left edge down
        const int C4     = (x2 - xa + 3) >> 2;          // float4 chunks per row, 1..32
        const int R      = y2 - y1;
        const int total4 = R * C4;                      // < 2^12
        const unsigned M = (C4 > 1) ? (0xFFFFFFFFu / (unsigned)C4 + 1u) : 0u;

        float best = -INFINITY;
        int   bidx = 0x7fffffff;                        // global flat idx y*NW+x

        auto proc = [&](int idx, float4 v) {
            const int row = (C4 == 1) ? idx : (int)__umulhi((unsigned)idx, M);
            const int xb  = xa + (idx - row * C4) * 4;
            const int g   = (y1 + row) * NW + xb;
            // component order = increasing x = increasing flat idx; strict > keeps
            // the earliest occurrence (argmax tie semantics)
            const float v0 = (xb + 0 >= x1 && xb + 0 < x2) ? v.x : -INFINITY;
            const float v1 = (xb + 1 >= x1 && xb + 1 < x2) ? v.y : -INFINITY;
            const float v2 = (xb + 2 >= x1 && xb + 2 < x2) ? v.z : -INFINITY;
            const float v3 = (xb + 3 < x2) ? v.w : -INFINITY;
            if (v0 > best) { best = v0; bidx = g + 0; }
            if (v1 > best) { best = v1; bidx = g + 1; }
            if (v2 > best) { best = v2; bidx = g + 2; }
            if (v3 > best) { best = v3; bidx = g + 3; }
        };
        auto caddr = [&](int idx) {
            const int row = (C4 == 1) ? idx : (int)__umulhi((unsigned)idx, M);
            return (y1 + row) * (NW / 4) + (xa >> 2) + (idx - row * C4);
        };

        int idx = lane;
        // 4 chunk-loads in flight per iteration (16 values).
        for (; idx + 192 < total4; idx += 256) {
            const int a0 = caddr(idx), a1 = caddr(idx + 64), a2 = caddr(idx + 128), a3 = caddr(idx + 192);
            const float4 v0 = b4[a0];
            const float4 v1 = b4[a1];
            const float4 v2 = b4[a2];
            const float4 v3 = b4[a3];
            proc(idx, v0);
            proc(idx + 64, v1);
            proc(idx + 128, v2);
            proc(idx + 192, v3);
        }
        for (; idx < total4; idx += 64) proc(idx, b4[caddr(idx)]);

        // 64-lane shuffle argmax reduce; tie -> smaller flat index (argmax semantics)
        for (int off = 32; off >= 1; off >>= 1) {
            const float ov = __shfl_down(best, off);
            const int   oi = __shfl_down(bidx, off);
            if (ov > best || (ov == best && oi < bidx)) { best = ov; bidx = oi; }
        }

        if (lane == 0) {
            const int col = bidx & (NW - 1);
            const int row = bidx >> 7;
            float conf = best;
            if (conf < KP_CONF) conf = 0.0f;
            float* kout = out + OFF_KPS + (size_t)gi * (NK * 3) + k * 3;
            kout[0] = (float)col / sx;
            kout[1] = (float)row / sy;
            kout[2] = conf;
        }
    }
}

extern "C" void kernel_launch(void* const* d_in, const int* in_sizes, int n_in,
                              void* d_out, int out_size, void* d_ws, size_t ws_size,
                              hipStream_t stream) {
    const float* logits = (const float*)d_in[0];   // [4,100,2]
    const float* pboxes = (const float*)d_in[1];   // [4,100,4]
    const float* hm     = (const float*)d_in[2];   // [4,17,128,128]
    const int*   img_h  = (const int*)d_in[3];
    const int*   img_w  = (const int*)d_in[4];
    float* out = (float*)d_out;

    unsigned* flags  = (unsigned*)d_ws;            // [8]
    int*      wcount = (int*)((char*)d_ws + 64);   // [4]
    int2*     wlist  = (int2*)((char*)d_ws + 256); // [400], aligned

    fused_kernel<<<NBLK, 128, 0, stream>>>(logits, pboxes, hm, img_h, img_w,
                                           out, flags, wcount, wlist);
}

// Round 3
// 105.845 us; speedup vs baseline: 1.8470x; 1.8470x over previous
//
#include <hip/hip_runtime.h>
#include <cmath>
#include <cfloat>

// Problem constants (fixed by setup_inputs: B=4, Q=100, K=17, H=W=128).
constexpr int NB = 4;
constexpr int NQ = 100;
constexpr int NK = 17;
constexpr int NH = 128;
constexpr int NW = 128;

constexpr float HUMAN_CONF = 0.7f;
constexpr float KP_CONF    = 0.5f;
constexpr float NMS_THR    = 0.5f;

// Output layout (flat float32, reference return order):
//   scores  [NB*NQ]          offset 0
//   boxes   [NB*NQ*4]        offset NB*NQ
//   kps     [NB*NQ*NK*3]     offset NB*NQ*5
//   keep    [NB*NQ]          offset NB*NQ*5 + NB*NQ*NK*3
constexpr int OFF_BOXES = NB * NQ;
constexpr int OFF_KPS   = NB * NQ * 5;
constexpr int OFF_KEEP  = NB * NQ * 5 + NB * NQ * NK * 3;

constexpr int NBLK = 1024;            // 256 blocks per batch
constexpr int WAVES_PER_BATCH = (NBLK / NB) * 2;   // 512

// ---------------- Fused kernel, v2: redundant per-block NMS (no cross-block comms) ----------------
// Block blk is bound to batch b = blk & 3. Every block recomputes batch b's
// NMS (deterministic -> bit-identical across blocks; ~5 us of parallel VALU/LDS
// work), builds the per-original-box live-ROI table in LDS, then grid-strides
// one wave per (q, k) item over ALL NQ*NK items of its batch: dead items write
// their 3 zeros exactly once, live items scan the ROI. No workspace, no
// atomics, no spin, no inter-kernel graph edge.
__global__ __launch_bounds__(128) void fused_kernel(
    const float* __restrict__ logits,   // [NB,NQ,2]
    const float* __restrict__ pboxes,   // [NB,NQ,4] cxcywh in [0,1]
    const float* __restrict__ hm,       // [NB,NK,NH,NW]
    const int* __restrict__ img_h_p,    // scalar
    const int* __restrict__ img_w_p,    // scalar
    float* __restrict__ out)            // 22800 floats
{
    const int blk = blockIdx.x;
    const int t   = threadIdx.x;
    const int b   = blk & 3;            // batch
    const int sub = blk >> 2;           // 0..255 within batch

    __shared__ float sbx[NQ][4];          // xyxy image coords, original order
    __shared__ float ssc[NQ];             // softmax max prob
    __shared__ unsigned char sval[NQ];    // valid flag
    __shared__ int   sorder[NQ];          // sorted pos -> original idx
    __shared__ float sortb[NQ][4];        // boxes in sorted order
    __shared__ float sarea[NQ];
    __shared__ unsigned char ssv[NQ];     // valid in sorted order
    __shared__ unsigned long long smask0[NQ], smask1[NQ]; // IoU>thr bitmask per sorted row
    __shared__ unsigned long long skmask[2];              // keep bits (sorted positions)
    __shared__ unsigned long long svb[2];                 // sorted-valid ballot per wave
    __shared__ int sqpack[NQ];            // per-ORIGINAL-q: 0 = dead, else packed ROI

    // ---- Early heatmap touch: one 64B line per thread covers all 4.45 MB
    // (poison just evicted L3). Issued now, consumed (waited) after phase 1,
    // so the HBM latency hides under the NMS compute.
    float4 wv4 = make_float4(0.f, 0.f, 0.f, 0.f);
    const int  line = blk * 128 + t;
    const bool doW  = line < (NB * NK * NH * NW) / 16;
    if (doW) wv4 = ((const float4*)hm)[line * 4];

    // ================= Phase 1: NMS for batch b (verified round-1 math) =================
    const float iw = (float)img_w_p[0];
    const float ih = (float)img_h_p[0];
    const float sxl = (float)NW / iw;     // 0.25 exact for 512
    const float syl = (float)NH / ih;

    if (t < NQ) {
        // softmax over 2 classes; score = max prob, label==0 iff l0 >= l1
        const float l0 = logits[(b * NQ + t) * 2 + 0];
        const float l1 = logits[(b * NQ + t) * 2 + 1];
        const float m  = fmaxf(l0, l1);
        const float e0 = expf(l0 - m);
        const float e1 = expf(l1 - m);
        const float score = fmaxf(e0, e1) / (e0 + e1);
        const bool  lab0  = (l0 >= l1);

        const float cx = pboxes[(b * NQ + t) * 4 + 0];
        const float cy = pboxes[(b * NQ + t) * 4 + 1];
        const float w  = pboxes[(b * NQ + t) * 4 + 2];
        const float h  = pboxes[(b * NQ + t) * 4 + 3];
        sbx[t][0] = (cx - 0.5f * w) * iw;
        sbx[t][1] = (cy - 0.5f * h) * ih;
        sbx[t][2] = (cx + 0.5f * w) * iw;
        sbx[t][3] = (cy + 0.5f * h) * ih;
        ssc[t]  = score;
        sval[t] = (lab0 && score >= HUMAN_CONF) ? 1 : 0;
    }
    __syncthreads();

    // Rank by (key desc, index desc) == reverse of stable ascending argsort.
    if (t < NQ) {
        const float key = sval[t] ? ssc[t] : -INFINITY;
        int rank = 0;
        for (int j = 0; j < NQ; ++j) {
            const float kj = sval[j] ? ssc[j] : -INFINITY;
            if (kj > key || (kj == key && j > t)) rank++;
        }
        sorder[rank] = t;
    }
    __syncthreads();

    if (t < NQ) {
        const int oi = sorder[t];
        const float x1 = sbx[oi][0], y1 = sbx[oi][1], x2 = sbx[oi][2], y2 = sbx[oi][3];
        sortb[t][0] = x1; sortb[t][1] = y1; sortb[t][2] = x2; sortb[t][3] = y2;
        sarea[t] = fmaxf(x2 - x1, 0.0f) * fmaxf(y2 - y1, 0.0f);
        ssv[t]   = sval[oi];
    }
    __syncthreads();

    // Each sorted row t: bitmask over columns j with IoU(t,j) > thr.
    if (t < NQ) {
        unsigned long long m0 = 0ull, m1 = 0ull;
        const float ax1 = sortb[t][0], ay1 = sortb[t][1], ax2 = sortb[t][2], ay2 = sortb[t][3];
        const float aa = sarea[t];
        for (int j = 0; j < NQ; ++j) {
            const float lx = fmaxf(ax1, sortb[j][0]);
            const float ly = fmaxf(ay1, sortb[j][1]);
            const float rx = fminf(ax2, sortb[j][2]);
            const float ry = fminf(ay2, sortb[j][3]);
            const float wv = fmaxf(rx - lx, 0.0f);
            const float hv = fmaxf(ry - ly, 0.0f);
            const float inter = wv * hv;
            const float uni = aa + sarea[j] - inter;
            const float iou = inter / fmaxf(uni, 1e-9f);
            if (iou > NMS_THR) {
                if (j < 64) m0 |= 1ull << j; else m1 |= 1ull << (j - 64);
            }
        }
        smask0[t] = m0; smask1[t] = m1;
    }

    // Sorted-valid ballot (valid boxes occupy a prefix of sorted order).
    {
        const bool sv = (t < NQ) ? (ssv[t] != 0) : false;
        const unsigned long long vb = __ballot(sv);
        if ((t & 63) == 0) svb[t >> 6] = vb;
    }
    __syncthreads();

    // ffs-driven greedy over bitmasks (thread 0): one iteration per KEPT box.
    if (t == 0) {
        unsigned long long rem0 = svb[0], rem1 = svb[1];
        unsigned long long k0 = 0ull, k1 = 0ull;
        while (rem0 | rem1) {
            int i;
            unsigned long long bit0 = 0ull, bit1 = 0ull;
            if (rem0) { i = __builtin_ctzll(rem0); bit0 = 1ull << i; }
            else      { const int j = __builtin_ctzll(rem1); i = 64 + j; bit1 = 1ull << j; }
            k0 |= bit0; k1 |= bit1;
            rem0 &= ~(smask0[i] | bit0);
            rem1 &= ~(smask1[i] | bit1);
        }
        skmask[0] = k0; skmask[1] = k1;
    }
    __syncthreads();

    // Epilogue: every block computes kp/ROI per sorted position and fills the
    // per-original-q live table; only sub==0 blocks write scores/boxes/keep.
    if (t < NQ) {
        const int oi = sorder[t];
        const int kp = (t < 64) ? (int)((skmask[0] >> t) & 1ull)
                                : (int)((skmask[1] >> (t - 64)) & 1ull);

        const int bi0 = (int)sbx[oi][0];   // trunc toward zero == astype(int32)
        const int bi1 = (int)sbx[oi][1];
        const int bi2 = (int)sbx[oi][2];
        const int bi3 = (int)sbx[oi][3];

        // ROI bounds: int * 0.25f exact; trunc toward zero matches astype(int32).
        const int x1i = max((int)((float)bi0 * sxl), 0);
        const int y1i = max((int)((float)bi1 * syl), 0);
        const int x2i = min((int)((float)bi2 * sxl) + 1, NW);
        const int y2i = min((int)((float)bi3 * syl) + 1, NH);
        const bool live = kp && (x2i > x1i) && (y2i > y1i);

        // live => x2i >= 1 => pack != 0, so 0 is a safe dead sentinel.
        sqpack[oi] = live ? (x1i | (y1i << 8) | (x2i << 16) | (y2i << 24)) : 0;

        if (sub == 0) {
            const int gi = b * NQ + oi;
            out[gi] = ssc[oi] * (float)kp;
            out[OFF_BOXES + gi * 4 + 0] = (float)(bi0 * kp);
            out[OFF_BOXES + gi * 4 + 1] = (float)(bi1 * kp);
            out[OFF_BOXES + gi * 4 + 2] = (float)(bi2 * kp);
            out[OFF_BOXES + gi * 4 + 3] = (float)(bi3 * kp);
            out[OFF_KEEP + gi] = (float)kp;
        }
    }
    __syncthreads();

    // Consume the warm touch (waitcnt lands here, long after issue).
    if (doW) asm volatile("" :: "v"(wv4.x), "v"(wv4.y), "v"(wv4.z), "v"(wv4.w));

    // ================= Phase 2: one wave per (q, keypoint) item of batch b =================
    // Covers ALL NQ*NK items: dead items write their 3 zeros exactly once
    // (replaces the old zero-fill pass), live items scan the ROI.
    const int lane = t & 63;
    const int wvid = sub * 2 + (t >> 6);          // wave id within batch, 0..511

    for (int item = wvid; item < NQ * NK; item += WAVES_PER_BATCH) {
        const int q = item / NK;                  // const divisor -> magic mul
        const int k = item - q * NK;
        const int gi = b * NQ + q;
        float* kout = out + OFF_KPS + (size_t)gi * (NK * 3) + k * 3;

        const int pack = sqpack[q];               // wave-uniform LDS broadcast
        if (pack == 0) {                          // dead: write zeros, done
            if (lane < 3) kout[lane] = 0.0f;
            continue;
        }

        const int x1 = pack & 255;
        const int y1 = (pack >> 8) & 255;
        const int x2 = (pack >> 16) & 255;
        const int y2 = (pack >> 24) & 255;

        const float4* __restrict__ b4 =
            (const float4*)(hm + (size_t)(b * NK + k) * (NH * NW));   // 64KB-aligned

        const int xa     = x1 & ~3;                     // align ROI left edge down
        const int C4     = (x2 - xa + 3) >> 2;          // float4 chunks per row, 1..32
        const int R      = y2 - y1;
        const int total4 = R * C4;                      // < 2^12
        const unsigned M = (C4 > 1) ? (0xFFFFFFFFu / (unsigned)C4 + 1u) : 0u;

        float best = -INFINITY;
        int   bidx = 0x7fffffff;                        // global flat idx y*NW+x

        auto proc = [&](int idx, float4 v) {
            const int row = (C4 == 1) ? idx : (int)__umulhi((unsigned)idx, M);
            const int xb  = xa + (idx - row * C4) * 4;
            const int g   = (y1 + row) * NW + xb;
            // component order = increasing x = increasing flat idx; strict > keeps
            // the earliest occurrence (argmax tie semantics)
            const float v0 = (xb + 0 >= x1 && xb + 0 < x2) ? v.x : -INFINITY;
            const float v1 = (xb + 1 >= x1 && xb + 1 < x2) ? v.y : -INFINITY;
            const float v2 = (xb + 2 >= x1 && xb + 2 < x2) ? v.z : -INFINITY;
            const float v3 = (xb + 3 < x2) ? v.w : -INFINITY;
            if (v0 > best) { best = v0; bidx = g + 0; }
            if (v1 > best) { best = v1; bidx = g + 1; }
            if (v2 > best) { best = v2; bidx = g + 2; }
            if (v3 > best) { best = v3; bidx = g + 3; }
        };
        auto caddr = [&](int idx) {
            const int row = (C4 == 1) ? idx : (int)__umulhi((unsigned)idx, M);
            return (y1 + row) * (NW / 4) + (xa >> 2) + (idx - row * C4);
        };

        int idx = lane;
        // 4 chunk-loads in flight per iteration (16 values).
        for (; idx + 192 < total4; idx += 256) {
            const int a0 = caddr(idx), a1 = caddr(idx + 64), a2 = caddr(idx + 128), a3 = caddr(idx + 192);
            const float4 v0 = b4[a0];
            const float4 v1 = b4[a1];
            const float4 v2 = b4[a2];
            const float4 v3 = b4[a3];
            proc(idx, v0);
            proc(idx + 64, v1);
            proc(idx + 128, v2);
            proc(idx + 192, v3);
        }
        for (; idx < total4; idx += 64) proc(idx, b4[caddr(idx)]);

        // 64-lane shuffle argmax reduce; tie -> smaller flat index (argmax semantics)
        for (int off = 32; off >= 1; off >>= 1) {
            const float ov = __shfl_down(best, off);
            const int   oi = __shfl_down(bidx, off);
            if (ov > best || (ov == best && oi < bidx)) { best = ov; bidx = oi; }
        }

        if (lane == 0) {
            const int col = bidx & (NW - 1);
            const int row = bidx >> 7;
            float conf = best;
            if (conf < KP_CONF) conf = 0.0f;
            kout[0] = (float)col / sxl;
            kout[1] = (float)row / syl;
            kout[2] = conf;
        }
    }
}

extern "C" void kernel_launch(void* const* d_in, const int* in_sizes, int n_in,
                              void* d_out, int out_size, void* d_ws, size_t ws_size,
                              hipStream_t stream) {
    const float* logits = (const float*)d_in[0];   // [4,100,2]
    const float* pboxes = (const float*)d_in[1];   // [4,100,4]
    const float* hm     = (const float*)d_in[2];   // [4,17,128,128]
    const int*   img_h  = (const int*)d_in[3];
    const int*   img_w  = (const int*)d_in[4];
    float* out = (float*)d_out;

    fused_kernel<<<NBLK, 128, 0, stream>>>(logits, pboxes, hm, img_h, img_w, out);
}

// Round 4
// 96.835 us; speedup vs baseline: 2.0188x; 1.0930x over previous
//
#include <hip/hip_runtime.h>
#include <cmath>
#include <cfloat>

// Problem constants (fixed by setup_inputs: B=4, Q=100, K=17, H=W=128).
constexpr int NB = 4;
constexpr int NQ = 100;
constexpr int NK = 17;
constexpr int NH = 128;
constexpr int NW = 128;

constexpr float HUMAN_CONF = 0.7f;
constexpr float KP_CONF    = 0.5f;
constexpr float NMS_THR    = 0.5f;

// Output layout (flat float32, reference return order):
//   scores  [NB*NQ]          offset 0
//   boxes   [NB*NQ*4]        offset NB*NQ
//   kps     [NB*NQ*NK*3]     offset NB*NQ*5
//   keep    [NB*NQ]          offset NB*NQ*5 + NB*NQ*NK*3
constexpr int OFF_BOXES = NB * NQ;
constexpr int OFF_KPS   = NB * NQ * 5;
constexpr int OFF_KEEP  = NB * NQ * 5 + NB * NQ * NK * 3;

constexpr int NBLK = 1024;            // 256 blocks per batch
constexpr int WAVES_PER_BATCH = (NBLK / NB) * 2;   // 512

// ---------------- Fused kernel, v3: ILP-optimized redundant per-block NMS ----------------
// Round-3 post-mortem showed phase-1 NMS was ~40us of exposed LDS latency
// (serial dependent scalar LDS reads, 2 waves/SIMD). v3 keeps identical
// arithmetic but restructures data movement: rank in RANK space with a
// precomputed key array (unroll x4), IoU over the V valid boxes only via a
// padded float4 table (b128 broadcast reads, unroll x4), greedy over register-
// resident mask rows fetched by __shfl instead of dependent LDS reads, and
// outputs written by ORIGINAL index (no sorder gather, 2 fewer barriers).
__global__ __launch_bounds__(128) void fused_kernel(
    const float* __restrict__ logits,   // [NB,NQ,2]
    const float* __restrict__ pboxes,   // [NB,NQ,4] cxcywh in [0,1]
    const float* __restrict__ hm,       // [NB,NK,NH,NW]
    const int* __restrict__ img_h_p,    // scalar
    const int* __restrict__ img_w_p,    // scalar
    float* __restrict__ out)            // 22800 floats
{
    const int blk = blockIdx.x;
    const int t   = threadIdx.x;
    const int b   = blk & 3;            // batch
    const int sub = blk >> 2;           // 0..255 within batch

    __shared__ float  skey[NQ];                 // valid ? score : -inf (original idx)
    __shared__ float4 srtb[104];                // rank -> xyxy box, zero-padded to 104
    __shared__ unsigned long long smask0[NQ], smask1[NQ]; // IoU>thr bitmask per RANK row
    __shared__ unsigned long long svb[2];       // per-wave valid ballot
    __shared__ unsigned long long skmask[2];    // keep bits (rank space)
    __shared__ int sqpack[NQ];                  // per-ORIGINAL-q: 0 = dead, else packed ROI

    // ---- Early heatmap touch: one 64B line per thread covers all 4.45 MB
    // (poison just evicted L3). Consumed after phase 1 -> latency hidden.
    float4 wv4 = make_float4(0.f, 0.f, 0.f, 0.f);
    const int  line = blk * 128 + t;
    const bool doW  = line < (NB * NK * NH * NW) / 16;
    if (doW) wv4 = ((const float4*)hm)[line * 4];

    const float iw = (float)img_w_p[0];
    const float ih = (float)img_h_p[0];
    const float sxl = (float)NW / iw;     // 0.25 exact for 512
    const float syl = (float)NH / ih;

    // ================= Phase 0: per-box score/valid/box (registers) =================
    if (t < 104) srtb[t] = make_float4(0.f, 0.f, 0.f, 0.f);   // pad rows -> IoU 0

    float score = 0.f, x1 = 0.f, y1 = 0.f, x2 = 0.f, y2 = 0.f;
    bool valid = false;
    if (t < NQ) {
        const float2 lg = ((const float2*)logits)[b * NQ + t];   // 8B aligned
        const float m  = fmaxf(lg.x, lg.y);
        const float e0 = expf(lg.x - m);
        const float e1 = expf(lg.y - m);
        score = fmaxf(e0, e1) / (e0 + e1);
        const bool lab0 = (lg.x >= lg.y);

        const float4 pb = ((const float4*)pboxes)[b * NQ + t];   // 16B aligned
        x1 = (pb.x - 0.5f * pb.z) * iw;
        y1 = (pb.y - 0.5f * pb.w) * ih;
        x2 = (pb.x + 0.5f * pb.z) * iw;
        y2 = (pb.y + 0.5f * pb.w) * ih;

        valid = lab0 && (score >= HUMAN_CONF);
        skey[t] = valid ? score : -INFINITY;
    }
    {
        const unsigned long long vb = __ballot(valid);
        if ((t & 63) == 0) svb[t >> 6] = vb;
    }
    __syncthreads();   // A

    const int V = __popcll(svb[0]) + __popcll(svb[1]);   // # valid (uniform)

    // ================= Phase 1: rank (desc key, desc index) + scatter by rank ========
    // rank = #{j : key_j > key_t || (key_j == key_t && j > t)}; valid boxes get
    // ranks 0..V-1 (all invalid keys are -inf). Unroll x4 -> 4 LDS reads in flight.
    int r = 0;
    if (t < NQ) {
        const float key = valid ? score : -INFINITY;
        for (int j = 0; j < NQ; j += 4) {
            const float a0 = skey[j + 0];
            const float a1 = skey[j + 1];
            const float a2 = skey[j + 2];
            const float a3 = skey[j + 3];
            r += (a0 > key || (a0 == key && (j + 0) > t)) ? 1 : 0;
            r += (a1 > key || (a1 == key && (j + 1) > t)) ? 1 : 0;
            r += (a2 > key || (a2 == key && (j + 2) > t)) ? 1 : 0;
            r += (a3 > key || (a3 == key && (j + 3) > t)) ? 1 : 0;
        }
        if (valid) srtb[r] = make_float4(x1, y1, x2, y2);
    }
    __syncthreads();   // B

    // ================= Phase 2: IoU bitmask rows (rank space, valid rows only) =======
    if (valid) {
        unsigned long long m0 = 0ull, m1 = 0ull;
        const float aa = fmaxf(x2 - x1, 0.f) * fmaxf(y2 - y1, 0.f);
        const int Vp = (V + 3) & ~3;                 // padded rows give IoU 0
        for (int j = 0; j < Vp; j += 4) {
            #pragma unroll
            for (int u = 0; u < 4; ++u) {
                const float4 bb = srtb[j + u];       // broadcast b128 read
                const float ba = fmaxf(bb.z - bb.x, 0.f) * fmaxf(bb.w - bb.y, 0.f);
                const float lx = fmaxf(x1, bb.x);
                const float ly = fmaxf(y1, bb.y);
                const float rx = fminf(x2, bb.z);
                const float ry = fminf(y2, bb.w);
                const float wv = fmaxf(rx - lx, 0.f);
                const float hv = fmaxf(ry - ly, 0.f);
                const float inter = wv * hv;
                const float uni = aa + ba - inter;
                const float iou = inter / fmaxf(uni, 1e-9f);   // identical expr to ref path
                if (iou > NMS_THR) {
                    const int jj = j + u;
                    if (jj < 64) m0 |= 1ull << jj; else m1 |= 1ull << (jj - 64);
                }
            }
        }
        smask0[r] = m0; smask1[r] = m1;
    }
    __syncthreads();   // C

    // ================= Phase 3: greedy keep via register rows + shfl (wave 0) ========
    if (t < 64) {
        // Lane l holds rank-row l (garbage for l >= V -- never selected, since
        // rem only ever contains bits < V).
        const unsigned long long rm0 = smask0[t];
        const unsigned long long rm1 = smask1[t];

        unsigned long long rem0 = (V >= 64) ? ~0ull : ((1ull << V) - 1ull);
        unsigned long long rem1 = 0ull;
        if (V > 64) { const int v1 = V - 64; rem1 = (v1 >= 64) ? ~0ull : ((1ull << v1) - 1ull); }

        unsigned long long k0 = 0ull, k1 = 0ull;
        while (rem0 | rem1) {
            int i;
            unsigned long long bit0 = 0ull, bit1 = 0ull;
            if (rem0) { i = __builtin_ctzll(rem0); bit0 = 1ull << i; }
            else      { const int j = __builtin_ctzll(rem1); i = 64 + j; bit1 = 1ull << j; }
            k0 |= bit0; k1 |= bit1;
            unsigned long long row0, row1;
            if (i < 64) {                    // fast path: 2 shuffles (~10 cy)
                row0 = __shfl(rm0, i);
                row1 = __shfl(rm1, i);
            } else {                         // rare fallback: LDS broadcast read
                row0 = smask0[i];
                row1 = smask1[i];
            }
            rem0 &= ~(row0 | bit0);          // self-clear handles degenerate boxes
            rem1 &= ~(row1 | bit1);
        }
        if (t == 0) { skmask[0] = k0; skmask[1] = k1; }
    }
    __syncthreads();   // D

    // ================= Phase 4: epilogue by ORIGINAL index =================
    if (t < NQ) {
        const unsigned long long k0s = skmask[0];
        const unsigned long long k1s = skmask[1];
        int kp = 0;
        if (valid) kp = (r < 64) ? (int)((k0s >> r) & 1ull)
                                 : (int)((k1s >> (r - 64)) & 1ull);

        const int bi0 = (int)x1;   // trunc toward zero == astype(int32)
        const int bi1 = (int)y1;
        const int bi2 = (int)x2;
        const int bi3 = (int)y2;

        // ROI bounds: int * 0.25f exact; trunc toward zero matches astype(int32).
        const int x1i = max((int)((float)bi0 * sxl), 0);
        const int y1i = max((int)((float)bi1 * syl), 0);
        const int x2i = min((int)((float)bi2 * sxl) + 1, NW);
        const int y2i = min((int)((float)bi3 * syl) + 1, NH);
        const bool live = kp && (x2i > x1i) && (y2i > y1i);

        // live => x2i >= 1 => pack != 0, so 0 is a safe dead sentinel.
        sqpack[t] = live ? (x1i | (y1i << 8) | (x2i << 16) | (y2i << 24)) : 0;

        if (sub == 0) {
            const int gi = b * NQ + t;
            out[gi] = score * (float)kp;
            out[OFF_BOXES + gi * 4 + 0] = (float)(bi0 * kp);
            out[OFF_BOXES + gi * 4 + 1] = (float)(bi1 * kp);
            out[OFF_BOXES + gi * 4 + 2] = (float)(bi2 * kp);
            out[OFF_BOXES + gi * 4 + 3] = (float)(bi3 * kp);
            out[OFF_KEEP + gi] = (float)kp;
        }
    }
    __syncthreads();   // E

    // Consume the warm touch (waitcnt lands here, long after issue).
    if (doW) asm volatile("" :: "v"(wv4.x), "v"(wv4.y), "v"(wv4.z), "v"(wv4.w));

    // ================= Phase 5: one wave per (q, keypoint) item of batch b =================
    // Covers ALL NQ*NK items: dead items write their 3 zeros exactly once,
    // live items scan the ROI. (Byte-identical to verified round-3 phase 2.)
    const int lane = t & 63;
    const int wvid = sub * 2 + (t >> 6);          // wave id within batch, 0..511

    for (int item = wvid; item < NQ * NK; item += WAVES_PER_BATCH) {
        const int q = item / NK;                  // const divisor -> magic mul
        const int k = item - q * NK;
        const int gi = b * NQ + q;
        float* kout = out + OFF_KPS + (size_t)gi * (NK * 3) + k * 3;

        const int pack = sqpack[q];               // wave-uniform LDS broadcast
        if (pack == 0) {                          // dead: write zeros, done
            if (lane < 3) kout[lane] = 0.0f;
            continue;
        }

        const int x1r = pack & 255;
        const int y1r = (pack >> 8) & 255;
        const int x2r = (pack >> 16) & 255;
        const int y2r = (pack >> 24) & 255;

        const float4* __restrict__ b4 =
            (const float4*)(hm + (size_t)(b * NK + k) * (NH * NW));   // 64KB-aligned

        const int xa     = x1r & ~3;                    // align ROI left edge down
        const int C4     = (x2r - xa + 3) >> 2;         // float4 chunks per row, 1..32
        const int R      = y2r - y1r;
        const int total4 = R * C4;                      // < 2^12
        const unsigned M = (C4 > 1) ? (0xFFFFFFFFu / (unsigned)C4 + 1u) : 0u;

        float best = -INFINITY;
        int   bidx = 0x7fffffff;                        // global flat idx y*NW+x

        auto proc = [&](int idx, float4 v) {
            const int row = (C4 == 1) ? idx : (int)__umulhi((unsigned)idx, M);
            const int xb  = xa + (idx - row * C4) * 4;
            const int g   = (y1r + row) * NW + xb;
            // component order = increasing x = increasing flat idx; strict > keeps
            // the earliest occurrence (argmax tie semantics)
            const float v0 = (xb + 0 >= x1r && xb + 0 < x2r) ? v.x : -INFINITY;
            const float v1 = (xb + 1 >= x1r && xb + 1 < x2r) ? v.y : -INFINITY;
            const float v2 = (xb + 2 >= x1r && xb + 2 < x2r) ? v.z : -INFINITY;
            const float v3 = (xb + 3 < x2r) ? v.w : -INFINITY;
            if (v0 > best) { best = v0; bidx = g + 0; }
            if (v1 > best) { best = v1; bidx = g + 1; }
            if (v2 > best) { best = v2; bidx = g + 2; }
            if (v3 > best) { best = v3; bidx = g + 3; }
        };
        auto caddr = [&](int idx) {
            const int row = (C4 == 1) ? idx : (int)__umulhi((unsigned)idx, M);
            return (y1r + row) * (NW / 4) + (xa >> 2) + (idx - row * C4);
        };

        int idx = lane;
        // 4 chunk-loads in flight per iteration (16 values).
        for (; idx + 192 < total4; idx += 256) {
            const int a0 = caddr(idx), a1 = caddr(idx + 64), a2 = caddr(idx + 128), a3 = caddr(idx + 192);
            const float4 v0 = b4[a0];
            const float4 v1 = b4[a1];
            const float4 v2 = b4[a2];
            const float4 v3 = b4[a3];
            proc(idx, v0);
            proc(idx + 64, v1);
            proc(idx + 128, v2);
            proc(idx + 192, v3);
        }
        for (; idx < total4; idx += 64) proc(idx, b4[caddr(idx)]);

        // 64-lane shuffle argmax reduce; tie -> smaller flat index (argmax semantics)
        for (int off = 32; off >= 1; off >>= 1) {
            const float ov = __shfl_down(best, off);
            const int   oi = __shfl_down(bidx, off);
            if (ov > best || (ov == best && oi < bidx)) { best = ov; bidx = oi; }
        }

        if (lane == 0) {
            const int col = bidx & (NW - 1);
            const int row = bidx >> 7;
            float conf = best;
            if (conf < KP_CONF) conf = 0.0f;
            kout[0] = (float)col / sxl;
            kout[1] = (float)row / syl;
            kout[2] = conf;
        }
    }
}

extern "C" void kernel_launch(void* const* d_in, const int* in_sizes, int n_in,
                              void* d_out, int out_size, void* d_ws, size_t ws_size,
                              hipStream_t stream) {
    const float* logits = (const float*)d_in[0];   // [4,100,2]
    const float* pboxes = (const float*)d_in[1];   // [4,100,4]
    const float* hm     = (const float*)d_in[2];   // [4,17,128,128]
    const int*   img_h  = (const int*)d_in[3];
    const int*   img_w  = (const int*)d_in[4];
    float* out = (float*)d_out;

    fused_kernel<<<NBLK, 128, 0, stream>>>(logits, pboxes, hm, img_h, img_w, out);
}